// Round 4
// baseline (634.967 us; speedup 1.0000x reference)
//
#include <hip/hip_runtime.h>
#include <math.h>

// Problem constants (from reference)
constexpr int NQ    = 14;        // qubits
constexpr int DIM   = 16384;     // 2^14 state dim
constexpr int BATCH = 4;
constexpr int SEQ   = 2048;
constexpr int NPOS  = BATCH * SEQ;   // 8192 (b,s) positions
constexpr int TPB   = 256;           // threads per block
constexpr int P     = 16;            // positions per block (compute kernel)
constexpr int NBLK  = NPOS / P;      // 512 blocks

// Output is [B,S,DIM] where only d=0 of each (b,s) row is nonzero:
//   out[b,s,0] = total * softmax(z)[0],  z = tanh(x*W1+b1) @ W2 + b2
//
// R4: SPLIT the work. R0-R3 established (4 schedule variants, all ~226-237us
// for the fused kernel) that a compute kernel's store stream tops out at
// ~4.8 TB/s, while rocclr fillBufferAligned sustains 6.28 TB/s on this very
// buffer every harness iteration. The 1.07 GiB of zeros depends on nothing,
// so: (1) hipMemsetAsync zeroes the output at fill rate (~171us; memset is
// graph-capture-safe — the harness itself enqueues hipMemsetAsync); (2) a
// pure-compute kernel (P=16 positions/block -> W2 read once per 16 positions,
// ~470MB L2 traffic) computes softmax denominators and writes only the 8192
// nonzero complex values. Main loop has NO stores and NO LDS writes; z[d=0]
// is recomputed in the epilogue from W2[:,0].
// Expected: 342 (harness poison) + ~171 (memset) + ~32 (compute) ~= 550us.

template <bool CPLX>
__global__ void __launch_bounds__(TPB)
qenc_compute(const float* __restrict__ x,     // [8192]
             const float* __restrict__ rot,   // [14,3]
             const float* __restrict__ ent,   // [13]
             const float* __restrict__ W1,    // [14]
             const float* __restrict__ b1,    // [14]
             const float* __restrict__ W2,    // [14,16384]
             const float* __restrict__ b2,    // [16384]
             float* __restrict__ out)
{
    __shared__ float sh_h[P * 16];   // h rows padded to 16 floats (float4-aligned)
    __shared__ float red[4][P];      // 4 waves x P partial denominators
    __shared__ float sh_tot_re, sh_tot_im;

    const int tid  = threadIdx.x;
    const int wid  = tid >> 6;
    const int lane = tid & 63;
    const long long pos0 = (long long)blockIdx.x * P;

    // --- prologue: h = tanh(x*W1 + b1) for our P positions ---
    if (tid < P * NQ) {               // 224 threads
        const int p = tid / NQ;
        const int k = tid - p * NQ;
        sh_h[p * 16 + k] = tanhf(x[pos0 + p] * W1[k] + b1[k]);
    }
    // total = prod(rot_factors) * prod(ent_factors) — one idle thread
    if (tid == 240) {
        float tre = 1.0f, tim = 0.0f;
        for (int q = 0; q < NQ; ++q) {
            const float a0 = 0.5f * rot[q * 3 + 0];
            const float a1 = 0.5f * rot[q * 3 + 1];
            const float a2 = 0.5f * rot[q * 3 + 2];
            const float fre = cosf(a0) * cosf(a1) * cosf(a2);
            const float fim = sinf(a0) * sinf(a1) * sinf(a2);
            const float nre = tre * fre - tim * fim;
            const float nim = tre * fim + tim * fre;
            tre = nre; tim = nim;
        }
        for (int q = 0; q < NQ - 1; ++q) {
            const float cs  = 1.0f / (1.0f + __expf(-ent[q]));
            const float nre = tre * cs - tim * (1.0f - cs);
            const float nim = tre * (1.0f - cs) + tim * cs;
            tre = nre; tim = nim;
        }
        sh_tot_re = tre; sh_tot_im = tim;
    }
    __syncthreads();

    float acc[P];
#pragma unroll
    for (int p = 0; p < P; ++p) acc[p] = 0.0f;

    // --- main loop: pure compute, no stores. 4 consecutive d per thread. ---
    // |z| <~ 1.2 (|h|<=1, W2 ~ N(0,0.01)) so plain exp-sum is numerically fine
    // (the reference's max-subtraction cancels exactly in the d=0 ratio).
    constexpr int ITERS = DIM / (4 * TPB);   // 16
    for (int i = 0; i < ITERS; ++i) {
        const int d = 4 * (tid + TPB * i);
        float4 wv[NQ];
#pragma unroll
        for (int k = 0; k < NQ; ++k)
            wv[k] = *reinterpret_cast<const float4*>(W2 + (size_t)k * DIM + d);
        const float4 bb = *reinterpret_cast<const float4*>(b2 + d);

#pragma unroll
        for (int p = 0; p < P; ++p) {
            // vector-load this position's h row from LDS (broadcast reads)
            const float4 ha = *reinterpret_cast<const float4*>(&sh_h[p * 16 + 0]);
            const float4 hb = *reinterpret_cast<const float4*>(&sh_h[p * 16 + 4]);
            const float4 hc = *reinterpret_cast<const float4*>(&sh_h[p * 16 + 8]);
            const float2 he = *reinterpret_cast<const float2*>(&sh_h[p * 16 + 12]);
            const float hh[NQ] = {ha.x, ha.y, ha.z, ha.w,
                                  hb.x, hb.y, hb.z, hb.w,
                                  hc.x, hc.y, hc.z, hc.w,
                                  he.x, he.y};
            float za = bb.x, zb = bb.y, zc = bb.z, zd = bb.w;
#pragma unroll
            for (int k = 0; k < NQ; ++k) {
                za = fmaf(hh[k], wv[k].x, za);
                zb = fmaf(hh[k], wv[k].y, zb);
                zc = fmaf(hh[k], wv[k].z, zc);
                zd = fmaf(hh[k], wv[k].w, zd);
            }
            acc[p] += (__expf(za) + __expf(zb)) + (__expf(zc) + __expf(zd));
        }
    }

    // --- reduction: wave shuffle, then 4 partials per p in LDS ---
#pragma unroll
    for (int p = 0; p < P; ++p) {
        float v = acc[p];
#pragma unroll
        for (int off = 32; off > 0; off >>= 1)
            v += __shfl_down(v, off, 64);
        if (lane == 0) red[wid][p] = v;
    }
    __syncthreads();

    // --- epilogue: 16 threads, one position each ---
    if (tid < P) {
        const float denom = (red[0][tid] + red[1][tid]) + (red[2][tid] + red[3][tid]);
        // recompute z[d=0] for this position (14 L2-hot scalar loads)
        float z0 = b2[0];
#pragma unroll
        for (int k = 0; k < NQ; ++k)
            z0 = fmaf(sh_h[tid * 16 + k], W2[(size_t)k * DIM], z0);
        const float w0 = __expf(z0) / denom;
        const size_t stride = CPLX ? 2 * (size_t)DIM : (size_t)DIM;
        float* rowp = out + (size_t)(pos0 + tid) * stride;
        rowp[0] = sh_tot_re * w0;
        if constexpr (CPLX) rowp[1] = sh_tot_im * w0;
    }
}

extern "C" void kernel_launch(void* const* d_in, const int* in_sizes, int n_in,
                              void* d_out, int out_size, void* d_ws, size_t ws_size,
                              hipStream_t stream) {
    (void)in_sizes; (void)n_in; (void)d_ws; (void)ws_size;
    const float* x   = (const float*)d_in[0];
    const float* rot = (const float*)d_in[1];
    const float* ent = (const float*)d_in[2];
    const float* W1  = (const float*)d_in[3];
    const float* b1  = (const float*)d_in[4];
    const float* W2  = (const float*)d_in[5];
    const float* b2  = (const float*)d_in[6];
    float* out = (float*)d_out;

    const long long cplx_elems = (long long)NPOS * 2LL * DIM;  // 268,435,456
    if ((long long)out_size >= cplx_elems) {
        // zero the compared region at fill rate, then write the 8192 nonzeros
        hipMemsetAsync(d_out, 0, (size_t)NPOS * 2 * (size_t)DIM * sizeof(float), stream);
        qenc_compute<true><<<NBLK, TPB, 0, stream>>>(x, rot, ent, W1, b1, W2, b2, out);
    } else {
        hipMemsetAsync(d_out, 0, (size_t)NPOS * (size_t)DIM * sizeof(float), stream);
        qenc_compute<false><<<NBLK, TPB, 0, stream>>>(x, rot, ent, W1, b1, W2, b2, out);
    }
}

// Round 6
// 633.334 us; speedup vs baseline: 1.0026x; 1.0026x over previous
//
#include <hip/hip_runtime.h>
#include <math.h>

// Problem constants (from reference)
constexpr int NQ    = 14;        // qubits
constexpr int DIM   = 16384;     // 2^14 state dim
constexpr int BATCH = 4;
constexpr int SEQ   = 2048;
constexpr int NPOS  = BATCH * SEQ;   // 8192 (b,s) positions
constexpr int TPB   = 256;

// compute blocks: 16 positions each, 4 per wave (wave-independent)
constexpr int PCOMP = 16;
constexpr int NCOMP = NPOS / PCOMP;          // 512
// fill blocks: 2 rows each
constexpr int RPF   = 2;
constexpr int NFILL = NPOS / RPF;            // 4096

typedef float vf4 __attribute__((ext_vector_type(4)));

__device__ __forceinline__ float uniform_f(float v) {
    return __int_as_float(__builtin_amdgcn_readfirstlane(__float_as_int(v)));
}

// out[b,s,:] is zero except the first complex element:
//   out[b,s,0] = total * softmax(z)[0],  z = tanh(x*W1+b1) @ W2 + b2
//
// R5 (resubmit — R5 bench never ran: GPUAcquisitionTimeout):
// ONE kernel, two block roles, DISJOINT byte ranges (no ordering needed):
//   - blocks [0,NCOMP): compute denominators; write ONLY the 16-byte row head
//     {re, im, 0, 0} of each owned row. Per-wave position ownership (4 pos,
//     h in 56 SGPRs via readfirstlane) -> no LDS in main loop, no cross-wave
//     reduction, ~90 VGPR.
//   - blocks [NCOMP, NCOMP+NFILL): zero floats [4, ROW_F) of 2 rows each as a
//     pure nt-store stream (fillBuffer-shaped, no waits, no deps).
// Rationale: R0-R3 showed the fused kernel was ALREADY at combined HBM
// roofline (1.07GB W + ~0.35GB W2 refetch at ~6.2 TB/s); R4 showed
// memset+compute SERIALIZED costs more, and graph-captured memset may not hit
// fill rate. This removes the read traffic from the write stream's critical
// path and overlaps compute under the irreducible 1.07GB write (~171us).

template <bool CPLX>
__global__ void __launch_bounds__(TPB)
qenc_mega(const float* __restrict__ x,     // [8192]
          const float* __restrict__ rot,   // [14,3]
          const float* __restrict__ ent,   // [13]
          const float* __restrict__ W1,    // [14]
          const float* __restrict__ b1,    // [14]
          const float* __restrict__ W2,    // [14,16384]
          const float* __restrict__ b2,    // [16384]
          float* __restrict__ out)
{
    constexpr size_t ROW_F = CPLX ? 2 * (size_t)DIM : (size_t)DIM; // floats/row
    const int tid = threadIdx.x;

    if (blockIdx.x >= NCOMP) {
        // ---------------- fill block: zero floats [4, ROW_F) of RPF rows ----
        const size_t fb = (size_t)blockIdx.x - NCOMP;
        float* row = out + fb * RPF * ROW_F;
        constexpr int Q4 = (int)(ROW_F / 4) - 1;     // float4s per row (8191/4095)
        constexpr int J  = (Q4 + TPB - 1) / TPB;     // 32 / 16
        vf4 z = {0.f, 0.f, 0.f, 0.f};
#pragma unroll
        for (int j = 0; j < J; ++j) {
            const int i = tid + TPB * j;
            if (i < Q4) {
                __builtin_nontemporal_store(z, reinterpret_cast<vf4*>(row + 4 + 4 * (size_t)i));
                __builtin_nontemporal_store(z, reinterpret_cast<vf4*>(row + ROW_F + 4 + 4 * (size_t)i));
            }
        }
        return;
    }

    // ---------------- compute block ----------------
    __shared__ float sh_h[PCOMP][NQ];
    __shared__ float sh_tot_re, sh_tot_im;

    const int wid  = tid >> 6;
    const int lane = tid & 63;
    const long long pos0 = (long long)blockIdx.x * PCOMP;

    // prologue: h = tanh(x*W1 + b1) for our 16 positions (224 threads)
    if (tid < PCOMP * NQ) {
        const int p = tid / NQ;
        const int k = tid - p * NQ;
        sh_h[p][k] = tanhf(x[pos0 + p] * W1[k] + b1[k]);
    }
    // total = prod(rot_factors) * prod(ent_factors) — one otherwise-idle thread
    if (tid == 240) {
        float tre = 1.0f, tim = 0.0f;
        for (int q = 0; q < NQ; ++q) {
            const float a0 = 0.5f * rot[q * 3 + 0];
            const float a1 = 0.5f * rot[q * 3 + 1];
            const float a2 = 0.5f * rot[q * 3 + 2];
            const float fre = cosf(a0) * cosf(a1) * cosf(a2);
            const float fim = sinf(a0) * sinf(a1) * sinf(a2);
            const float nre = tre * fre - tim * fim;
            const float nim = tre * fim + tim * fre;
            tre = nre; tim = nim;
        }
        for (int q = 0; q < NQ - 1; ++q) {
            const float cs  = 1.0f / (1.0f + __expf(-ent[q]));
            const float nre = tre * cs - tim * (1.0f - cs);
            const float nim = tre * (1.0f - cs) + tim * cs;
            tre = nre; tim = nim;
        }
        sh_tot_re = tre; sh_tot_im = tim;
    }
    __syncthreads();

    // wave wid owns positions pos0 + wid*4 + q (q=0..3); h -> SGPRs
    float h[4][NQ];
#pragma unroll
    for (int q = 0; q < 4; ++q)
#pragma unroll
        for (int k = 0; k < NQ; ++k)
            h[q][k] = uniform_f(sh_h[wid * 4 + q][k]);

    float acc[4] = {0.f, 0.f, 0.f, 0.f};
    float z0[4]  = {0.f, 0.f, 0.f, 0.f};   // valid on lane 0 only

    // main loop: each wave sweeps ALL of W2 (L1 reuse across the block's
    // waves); 4 consecutive d per lane per iter. No stores, no LDS.
    // |z| <~ 1.2 so plain exp-sum is numerically fine (the reference's
    // max-subtraction cancels exactly in the d=0 ratio).
    constexpr int ITERS = DIM / (4 * 64);   // 64
    for (int ii = 0; ii < ITERS; ++ii) {
        const int d = 4 * (lane + 64 * ii);
        float4 wv[NQ];
#pragma unroll
        for (int k = 0; k < NQ; ++k)
            wv[k] = *reinterpret_cast<const float4*>(W2 + (size_t)k * DIM + d);
        const float4 bb = *reinterpret_cast<const float4*>(b2 + d);
#pragma unroll
        for (int q = 0; q < 4; ++q) {
            float za = bb.x, zb = bb.y, zc = bb.z, zd = bb.w;
#pragma unroll
            for (int k = 0; k < NQ; ++k) {
                za = fmaf(h[q][k], wv[k].x, za);
                zb = fmaf(h[q][k], wv[k].y, zb);
                zc = fmaf(h[q][k], wv[k].z, zc);
                zd = fmaf(h[q][k], wv[k].w, zd);
            }
            if (d == 0) z0[q] = za;   // lane 0, ii == 0 only
            acc[q] += (__expf(za) + __expf(zb)) + (__expf(zc) + __expf(zd));
        }
    }

    // wave-level butterfly reduce -> lane 0 holds full denominators
#pragma unroll
    for (int q = 0; q < 4; ++q) {
#pragma unroll
        for (int off = 32; off > 0; off >>= 1)
            acc[q] += __shfl_down(acc[q], off, 64);
    }

    if (lane == 0) {
        const float tre = sh_tot_re, tim = sh_tot_im;
#pragma unroll
        for (int q = 0; q < 4; ++q) {
            const float w0 = __expf(z0[q]) / acc[q];
            vf4 v;
            if constexpr (CPLX) v = {tre * w0, tim * w0, 0.f, 0.f};
            else                v = {tre * w0, 0.f, 0.f, 0.f};
            *reinterpret_cast<vf4*>(out + (size_t)(pos0 + wid * 4 + q) * ROW_F) = v;
        }
    }
}

extern "C" void kernel_launch(void* const* d_in, const int* in_sizes, int n_in,
                              void* d_out, int out_size, void* d_ws, size_t ws_size,
                              hipStream_t stream) {
    (void)in_sizes; (void)n_in; (void)d_ws; (void)ws_size;
    const float* x   = (const float*)d_in[0];
    const float* rot = (const float*)d_in[1];
    const float* ent = (const float*)d_in[2];
    const float* W1  = (const float*)d_in[3];
    const float* b1  = (const float*)d_in[4];
    const float* W2  = (const float*)d_in[5];
    const float* b2  = (const float*)d_in[6];
    float* out = (float*)d_out;

    const long long cplx_elems = (long long)NPOS * 2LL * DIM;  // 268,435,456
    if ((long long)out_size >= cplx_elems) {
        qenc_mega<true><<<NCOMP + NFILL, TPB, 0, stream>>>(x, rot, ent, W1, b1, W2, b2, out);
    } else {
        qenc_mega<false><<<NCOMP + NFILL, TPB, 0, stream>>>(x, rot, ent, W1, b1, W2, b2, out);
    }
}